// Round 13
// baseline (481.178 us; speedup 1.0000x reference)
//
#include <hip/hip_runtime.h>
#include <stdint.h>

#define T_DIM 8192
#define C_DIM 2048
#define LCHUNK 32
#define NCHUNK (T_DIM / LCHUNK)   // 256

typedef unsigned short u16;
typedef __bf16 bf16x8_t __attribute__((ext_vector_type(8)));
typedef float f32x4_t __attribute__((ext_vector_type(4)));

__device__ __forceinline__ u16 f2bf(float f) {
    union { float f; uint32_t u; } x; x.f = f;
    uint32_t r = x.u + 0x7fffu + ((x.u >> 16) & 1u);
    return (u16)(r >> 16);
}
__device__ __forceinline__ float bf2f(u16 u) {
    union { uint32_t u; float f; } x; x.u = ((uint32_t)u) << 16;
    return x.f;
}
__device__ __forceinline__ void gload16(const void* g, void* l) {
    __builtin_amdgcn_global_load_lds((const __attribute__((address_space(1))) uint32_t*)g,
                                     (__attribute__((address_space(3))) uint32_t*)l, 16, 0, 0);
}
__device__ __forceinline__ f32x4_t mfma16(bf16x8_t a, bf16x8_t b, f32x4_t c) {
    return __builtin_amdgcn_mfma_f32_16x16x32_bf16(a, b, c, 0, 0, 0);
}

// ---- shared helper: 32x32 weight transpose tile: Wt[n][k] = bf16(W[k][n]) ----
__device__ __forceinline__ void transpose_tile(const float* __restrict__ W, u16* __restrict__ Tm,
                                               int bn, int bk, float* shf)
{
    const int tid = threadIdx.x;
    const int tx = tid & 31, ty = tid >> 5;
#pragma unroll
    for (int i = 0; i < 4; ++i)
        shf[(ty + 8 * i) * 33 + tx] = W[(size_t)(bk + ty + 8 * i) * C_DIM + bn + tx];
    __syncthreads();
#pragma unroll
    for (int i = 0; i < 4; ++i)
        Tm[(size_t)(bn + ty + 8 * i) * C_DIM + bk + tx] = f2bf(shf[tx * 33 + ty + 8 * i]);
}

// ---------------- prep: ln_mix (blocks 0..8191) U transpose Wk,Wv,Wr (blocks 8192..20479) --------
union F8 { float4 v[2]; float f[8]; };

__global__ __launch_bounds__(256)
void prep_kernel(const float* __restrict__ W0, const float* __restrict__ W1,
                 const float* __restrict__ W2, u16* __restrict__ Wt,
                 const float* __restrict__ x, const float* __restrict__ sx,
                 const float* __restrict__ lns, const float* __restrict__ lnb,
                 const float* __restrict__ tmk, const float* __restrict__ tmv,
                 const float* __restrict__ tmr,
                 u16* __restrict__ kx, u16* __restrict__ vx, u16* __restrict__ rx,
                 float* __restrict__ xx_last)
{
    __shared__ float shf[32 * 33];
    const int bid = blockIdx.x;
    const int tid = threadIdx.x;

    if (bid >= 8192) {
        const int z = (bid - 8192) >> 12;
        const int rem = (bid - 8192) & 4095;
        const float* W = (z == 0) ? W0 : (z == 1) ? W1 : W2;
        transpose_tile(W, Wt + (size_t)z * C_DIM * C_DIM, (rem & 63) * 32, (rem >> 6) * 32, shf);
        return;
    }

    const int t = bid;
    const size_t rowoff = (size_t)t * C_DIM;

    F8 a, p;
    const float4* xt = (const float4*)(x + rowoff);
    a.v[0] = xt[2 * tid]; a.v[1] = xt[2 * tid + 1];
    const float4* xp = (t == 0) ? (const float4*)sx : (const float4*)(x + rowoff - C_DIM);
    p.v[0] = xp[2 * tid]; p.v[1] = xp[2 * tid + 1];

    float s1 = 0.f, s2 = 0.f, s3 = 0.f, s4 = 0.f;
#pragma unroll
    for (int i = 0; i < 8; ++i) {
        s1 += a.f[i]; s2 += a.f[i] * a.f[i];
        s3 += p.f[i]; s4 += p.f[i] * p.f[i];
    }
#pragma unroll
    for (int off = 32; off; off >>= 1) {
        s1 += __shfl_down(s1, off);
        s2 += __shfl_down(s2, off);
        s3 += __shfl_down(s3, off);
        s4 += __shfl_down(s4, off);
    }
    float* red = shf;
    if ((tid & 63) == 0) {
        red[0 * 4 + (tid >> 6)] = s1; red[1 * 4 + (tid >> 6)] = s2;
        red[2 * 4 + (tid >> 6)] = s3; red[3 * 4 + (tid >> 6)] = s4;
    }
    __syncthreads();
    s1 = red[0] + red[1] + red[2] + red[3];
    s2 = red[4] + red[5] + red[6] + red[7];
    s3 = red[8] + red[9] + red[10] + red[11];
    s4 = red[12] + red[13] + red[14] + red[15];
    const float inv = 1.0f / (float)C_DIM;
    const float mu = s1 * inv;
    const float rstd = rsqrtf(s2 * inv - mu * mu + 1e-5f);
    const float mup = s3 * inv;
    const float rstdp = rsqrtf(s4 * inv - mup * mup + 1e-5f);

    F8 ls, lb, mk, mv, mr;
    { const float4* q = (const float4*)lns; ls.v[0] = q[2*tid]; ls.v[1] = q[2*tid+1]; }
    { const float4* q = (const float4*)lnb; lb.v[0] = q[2*tid]; lb.v[1] = q[2*tid+1]; }
    { const float4* q = (const float4*)tmk; mk.v[0] = q[2*tid]; mk.v[1] = q[2*tid+1]; }
    { const float4* q = (const float4*)tmv; mv.v[0] = q[2*tid]; mv.v[1] = q[2*tid+1]; }
    { const float4* q = (const float4*)tmr; mr.v[0] = q[2*tid]; mr.v[1] = q[2*tid+1]; }

    union { u16 u[8]; uint4 q; } ok, ov, orr;
#pragma unroll
    for (int i = 0; i < 8; ++i) {
        const float xxv  = (a.f[i] - mu) * rstd * ls.f[i] + lb.f[i];
        const float prev = (t == 0) ? p.f[i] : (p.f[i] - mup) * rstdp * ls.f[i] + lb.f[i];
        ok.u[i]  = f2bf(xxv * mk.f[i] + prev * (1.f - mk.f[i]));
        ov.u[i]  = f2bf(xxv * mv.f[i] + prev * (1.f - mv.f[i]));
        orr.u[i] = f2bf(xxv * mr.f[i] + prev * (1.f - mr.f[i]));
        if (t == T_DIM - 1) xx_last[tid * 8 + i] = xxv;
    }
    ((uint4*)(kx + rowoff))[tid] = ok.q;
    ((uint4*)(vx + rowoff))[tid] = ov.q;
    ((uint4*)(rx + rowoff))[tid] = orr.q;
}

// ---------------- dbuf GEMM core (r8-proven best: 37.8% MfmaUtil, 32 KiB, 4 blocks/CU) ----------
// mode 1: bf16 out, 2: sigmoid->bf16 out, 0: f32 out + resid
__device__ __forceinline__ void gemm_core_db(
    const u16* __restrict__ A, const u16* __restrict__ Bt,
    void* __restrict__ Cout, const float* __restrict__ resid,
    const int mode, const int N, const int K, const int m0, const int n0, u16* lds)
{
    const int tid = threadIdx.x;
    const int wave = tid >> 6, lane = tid & 63;
    const int wm = wave >> 1, wn = wave & 1;
    const int fr = lane & 15, fo = lane >> 4;
    const int sw = (fo ^ ((fr >> 1) & 3)) * 8;

    f32x4_t acc[4][4] = {};

    const int lrow = lane >> 2;
    const int scol = ((lane & 3) ^ ((lane >> 3) & 3)) * 8;
    const u16* gA = A  + (size_t)(m0 + wave * 16 + lrow) * K + scol;
    const u16* gB = Bt + (size_t)(n0 + wave * 16 + lrow) * K + scol;
    const size_t rk64 = (size_t)64 * K;
    const int dA = wave * 512;
    const int dB = 4096 + wave * 512;

    auto stage = [&](int t) {
        const int b = (t & 1) * 8192;
        const u16* ga = gA + (size_t)t * 32;
        const u16* gb = gB + (size_t)t * 32;
        gload16(ga,        lds + b + dA);
        gload16(ga + rk64, lds + b + dA + 2048);
        gload16(gb,        lds + b + dB);
        gload16(gb + rk64, lds + b + dB + 2048);
    };

    const int NT = K >> 5;
    stage(0);
    asm volatile("s_waitcnt vmcnt(0)" ::: "memory");
    asm volatile("s_barrier" ::: "memory");

    for (int t = 0; t < NT; ++t) {
        if (t + 1 < NT) stage(t + 1);
        const u16* lA = lds + (t & 1) * 8192 + (wm * 64 + fr) * 32;
        const u16* lB = lds + (t & 1) * 8192 + 4096 + (wn * 64 + fr) * 32;
        bf16x8_t a[4], b[4];
#pragma unroll
        for (int i = 0; i < 4; ++i) {
            a[i] = *(const bf16x8_t*)(lA + i * 512 + sw);
            b[i] = *(const bf16x8_t*)(lB + i * 512 + sw);
        }
        __builtin_amdgcn_s_setprio(1);
#pragma unroll
        for (int mi = 0; mi < 4; ++mi)
#pragma unroll
            for (int ni = 0; ni < 4; ++ni)
                acc[mi][ni] = mfma16(a[mi], b[ni], acc[mi][ni]);
        __builtin_amdgcn_s_setprio(0);
        asm volatile("s_waitcnt vmcnt(0)" ::: "memory");
        asm volatile("s_barrier" ::: "memory");
    }

    const int r4 = fo * 4;
#pragma unroll
    for (int mi = 0; mi < 4; ++mi) {
#pragma unroll
        for (int ni = 0; ni < 4; ++ni) {
            const int col = n0 + wn * 64 + ni * 16 + fr;
#pragma unroll
            for (int i = 0; i < 4; ++i) {
                const int row = m0 + wm * 64 + mi * 16 + r4 + i;
                float v = acc[mi][ni][i];
                if (mode == 0) {
                    ((float*)Cout)[(size_t)row * N + col] = v + resid[(size_t)row * N + col];
                } else if (mode == 1) {
                    ((u16*)Cout)[(size_t)row * N + col] = f2bf(v);
                } else {
                    const float s = 1.f / (1.f + __expf(-v));
                    ((u16*)Cout)[(size_t)row * N + col] = f2bf(s);
                }
            }
        }
    }
}

// k,v,r GEMMs (blocks 0..3071, dbuf core) U Wo transpose (blocks 3072..7167)
__global__ __launch_bounds__(256, 4)
void gemm_kvr(const u16* __restrict__ kx, const u16* __restrict__ vx, const u16* __restrict__ rxp,
              const float* __restrict__ Wo, u16* __restrict__ Wt,
              u16* __restrict__ kbuf, u16* __restrict__ vbuf, u16* __restrict__ rbuf)
{
    __shared__ u16 lds[16384];  // 32 KiB
    const int bid = blockIdx.x;
    if (bid >= 3072) {
        const int rem = bid - 3072;
        transpose_tile(Wo, Wt + (size_t)3 * C_DIM * C_DIM, (rem & 63) * 32, (rem >> 6) * 32,
                       (float*)lds);
        return;
    }
    const int which = bid >> 10;
    const int b = bid & 1023;
    const int m0 = (b & 63) << 7;           // m-fast: XCD round-robin shares B panel
    const int n0 = (b >> 6) << 7;
    const u16* A = (which == 0) ? kx : (which == 1) ? vx : rxp;
    const u16* B = Wt + (size_t)which * C_DIM * C_DIM;
    u16* C = (which == 0) ? kbuf : (which == 1) ? vbuf : rbuf;
    gemm_core_db(A, B, C, nullptr, (which == 2) ? 2 : 1, C_DIM, C_DIM, m0, n0, lds);
}

__global__ __launch_bounds__(256, 4)
void gemm_o(const u16* __restrict__ Aw, const u16* __restrict__ Wt3,
            float* __restrict__ out, const float* __restrict__ x)
{
    __shared__ u16 lds[16384];
    const int m0 = (int)(blockIdx.x & 63) << 7;
    const int n0 = (int)(blockIdx.x >> 6) << 7;
    gemm_core_db(Aw, Wt3, out, x, 0, C_DIM, C_DIM, m0, n0, lds);
}

// ---------------- WKV scan, chunked, 8 channels/thread (vectorized uint4 loads) ----------------
// LCHUNK=32, NCHUNK=256: grid 256 blocks x 256 threads; thread handles channels c0..c0+7.
__global__ __launch_bounds__(256)
void scan_partial(const u16* __restrict__ k, const u16* __restrict__ v,
                  const float* __restrict__ time_decay,
                  float* __restrict__ pA, float* __restrict__ pB, float* __restrict__ pP)
{
    const int j = blockIdx.x;
    const int c0 = threadIdx.x * 8;
    float w8[8];
    {
        F8 t; const float4* q = (const float4*)(time_decay + c0);
        t.v[0] = q[0]; t.v[1] = q[1];
#pragma unroll
        for (int i = 0; i < 8; ++i) w8[i] = -__expf(t.f[i]);
    }
    float aa[8] = {}, bb[8] = {}, pp[8];
#pragma unroll
    for (int i = 0; i < 8; ++i) pp[i] = -1e30f;

    const u16* kp = k + (size_t)j * LCHUNK * C_DIM + c0;
    const u16* vp = v + (size_t)j * LCHUNK * C_DIM + c0;
    for (int s = 0; s < LCHUNK; ++s) {
        union { uint4 q; u16 u[8]; } kq, vq;
        kq.q = *(const uint4*)kp; vq.q = *(const uint4*)vp;
        kp += C_DIM; vp += C_DIM;
#pragma unroll
        for (int i = 0; i < 8; ++i) {
            const float kk = bf2f(kq.u[i]);
            const float vv = bf2f(vq.u[i]);
            const float ww = w8[i] + pp[i];
            const float p2 = fmaxf(ww, kk);
            const float e1 = __expf(ww - p2);
            const float e2 = __expf(kk - p2);
            aa[i] = e1 * aa[i] + e2 * vv;
            bb[i] = e1 * bb[i] + e2;
            pp[i] = p2;
        }
    }
    const int o = j * C_DIM + c0;
    *(float4*)(pA + o)     = make_float4(aa[0], aa[1], aa[2], aa[3]);
    *(float4*)(pA + o + 4) = make_float4(aa[4], aa[5], aa[6], aa[7]);
    *(float4*)(pB + o)     = make_float4(bb[0], bb[1], bb[2], bb[3]);
    *(float4*)(pB + o + 4) = make_float4(bb[4], bb[5], bb[6], bb[7]);
    *(float4*)(pP + o)     = make_float4(pp[0], pp[1], pp[2], pp[3]);
    *(float4*)(pP + o + 4) = make_float4(pp[4], pp[5], pp[6], pp[7]);
}

// sequential cross-chunk combine with next-j prefetch (8 blocks x 256 threads)
__global__ __launch_bounds__(256)
void scan_combine(const float* __restrict__ pA, const float* __restrict__ pB,
                  const float* __restrict__ pP,
                  const float* __restrict__ aa_in, const float* __restrict__ bb_in,
                  const float* __restrict__ pp_in,
                  const float* __restrict__ time_decay,
                  float* __restrict__ sA, float* __restrict__ sB, float* __restrict__ sP)
{
    const int c = blockIdx.x * 256 + threadIdx.x;
    const float wL = -__expf(time_decay[c]) * (float)LCHUNK;
    float a = aa_in[c], b = bb_in[c], p = pp_in[c];
    float A = pA[c], B = pB[c], P = pP[c];
    for (int j = 0; j < NCHUNK; ++j) {
        const int o = j * C_DIM + c;
        float An = 0.f, Bn = 0.f, Pn = 0.f;
        if (j + 1 < NCHUNK) {               // prefetch next chunk's partials
            An = pA[o + C_DIM]; Bn = pB[o + C_DIM]; Pn = pP[o + C_DIM];
        }
        sA[o] = a; sB[o] = b; sP[o] = p;
        const float pd = p + wL;
        const float q = fmaxf(pd, P);
        const float e1 = __expf(pd - q), e2 = __expf(P - q);
        a = e1 * a + e2 * A;
        b = e1 * b + e2 * B;
        p = q;
        A = An; B = Bn; P = Pn;
    }
}

__global__ __launch_bounds__(256)
void scan_out(const u16* __restrict__ k, const u16* __restrict__ v,
              const u16* __restrict__ r,
              const float* __restrict__ time_decay, const float* __restrict__ time_first,
              const float* __restrict__ sA, const float* __restrict__ sB,
              const float* __restrict__ sP,
              u16* __restrict__ arwkv,
              float* __restrict__ aa_out, float* __restrict__ bb_out, float* __restrict__ pp_out)
{
    const int j = blockIdx.x;
    const int c0 = threadIdx.x * 8;
    float w8[8], u8[8];
    {
        F8 t; const float4* q = (const float4*)(time_decay + c0);
        t.v[0] = q[0]; t.v[1] = q[1];
#pragma unroll
        for (int i = 0; i < 8; ++i) w8[i] = -__expf(t.f[i]);
        const float4* q2 = (const float4*)(time_first + c0);
        t.v[0] = q2[0]; t.v[1] = q2[1];
#pragma unroll
        for (int i = 0; i < 8; ++i) u8[i] = t.f[i];
    }
    float aa[8], bb[8], pp[8];
    {
        const int so = j * C_DIM + c0;
        F8 t;
        t.v[0] = ((const float4*)(sA + so))[0]; t.v[1] = ((const float4*)(sA + so))[1];
#pragma unroll
        for (int i = 0; i < 8; ++i) aa[i] = t.f[i];
        t.v[0] = ((const float4*)(sB + so))[0]; t.v[1] = ((const float4*)(sB + so))[1];
#pragma unroll
        for (int i = 0; i < 8; ++i) bb[i] = t.f[i];
        t.v[0] = ((const float4*)(sP + so))[0]; t.v[1] = ((const float4*)(sP + so))[1];
#pragma unroll
        for (int i = 0; i < 8; ++i) pp[i] = t.f[i];
    }

    const size_t base = (size_t)j * LCHUNK * C_DIM + c0;
    const u16* kp = k + base;
    const u16* vp = v + base;
    const u16* rp = r + base;
    u16* op = arwkv + base;
    for (int s = 0; s < LCHUNK; ++s) {
        union { uint4 q; u16 u[8]; } kq, vq, rq, oq;
        kq.q = *(const uint4*)kp; vq.q = *(const uint4*)vp; rq.q = *(const uint4*)rp;
        kp += C_DIM; vp += C_DIM; rp += C_DIM;
#pragma unroll
        for (int i = 0; i < 8; ++i) {
            const float kk = bf2f(kq.u[i]);
            const float vv = bf2f(vq.u[i]);
            const float sr = bf2f(rq.u[i]);
            const float ww = u8[i] + kk;
            const float p = fmaxf(pp[i], ww);
            const float e1 = __expf(pp[i] - p);
            const float e2 = __expf(ww - p);
            const float o = (e1 * aa[i] + e2 * vv) / (e1 * bb[i] + e2);
            oq.u[i] = f2bf(sr * o);
            const float ww2 = w8[i] + pp[i];
            const float p2 = fmaxf(ww2, kk);
            const float f1 = __expf(ww2 - p2);
            const float f2 = __expf(kk - p2);
            aa[i] = f1 * aa[i] + f2 * vv;
            bb[i] = f1 * bb[i] + f2;
            pp[i] = p2;
        }
        *(uint4*)op = oq.q;
        op += C_DIM;
    }
    if (j == NCHUNK - 1) {
#pragma unroll
        for (int i = 0; i < 8; ++i) {
            aa_out[c0 + i] = aa[i]; bb_out[c0 + i] = bb[i]; pp_out[c0 + i] = pp[i];
        }
    }
}

// ---------------- launcher ----------------
extern "C" void kernel_launch(void* const* d_in, const int* in_sizes, int n_in,
                              void* d_out, int out_size, void* d_ws, size_t ws_size,
                              hipStream_t stream)
{
    (void)in_sizes; (void)n_in; (void)out_size; (void)ws_size;
    const float* x          = (const float*)d_in[0];
    const float* sx         = (const float*)d_in[1];
    const float* aa_in      = (const float*)d_in[2];
    const float* bb_in      = (const float*)d_in[3];
    const float* pp_in      = (const float*)d_in[4];
    const float* time_first = (const float*)d_in[5];
    const float* time_decay = (const float*)d_in[6];
    const float* tmk        = (const float*)d_in[7];
    const float* tmv        = (const float*)d_in[8];
    const float* tmr        = (const float*)d_in[9];
    const float* lns        = (const float*)d_in[10];
    const float* lnb        = (const float*)d_in[11];
    const float* Wk         = (const float*)d_in[12];
    const float* Wv         = (const float*)d_in[13];
    const float* Wr         = (const float*)d_in[14];
    const float* Wo         = (const float*)d_in[15];

    float* out     = (float*)d_out;
    float* xx_last = out + (size_t)T_DIM * C_DIM;
    float* aa_out  = xx_last + C_DIM;
    float* bb_out  = aa_out + C_DIM;
    float* pp_out  = bb_out + C_DIM;

    const size_t TC = (size_t)T_DIM * C_DIM;
    const size_t C2 = (size_t)C_DIM * C_DIM;
    u16* kx    = (u16*)d_ws;
    u16* vx    = kx + TC;
    u16* rx    = vx + TC;
    u16* Wt    = rx + TC;                  // 4*C2 bf16
    u16* kbuf  = Wt + 4 * C2;              // TC bf16
    u16* vbuf  = kbuf + TC;                // TC bf16
    u16* rbuf  = vbuf + TC;                // TC bf16
    float* pA  = (float*)(rbuf + TC);      // NCHUNK*C f32 each
    float* pB  = pA + (size_t)NCHUNK * C_DIM;
    float* pP  = pB + (size_t)NCHUNK * C_DIM;
    float* sA  = pP + (size_t)NCHUNK * C_DIM;
    float* sB  = sA + (size_t)NCHUNK * C_DIM;
    float* sP  = sB + (size_t)NCHUNK * C_DIM;
    u16* arwkv = rx;   // alias: rx dead after gemm_kvr

    // d1: ln_mix U transpose Wk,Wv,Wr
    prep_kernel<<<8192 + 12288, 256, 0, stream>>>(Wk, Wv, Wr, Wt,
                                                  x, sx, lns, lnb, tmk, tmv, tmr,
                                                  kx, vx, rx, xx_last);
    // d2: k,v,r GEMMs (dbuf core, 4 blocks/CU) U Wo transpose
    gemm_kvr<<<3072 + 4096, 256, 0, stream>>>(kx, vx, rx, Wo, Wt, kbuf, vbuf, rbuf);
    // d3-d5: chunked WKV scan (8 channels/thread, vectorized)
    scan_partial<<<NCHUNK, 256, 0, stream>>>(kbuf, vbuf, time_decay, pA, pB, pP);
    scan_combine<<<C_DIM / 256, 256, 0, stream>>>(pA, pB, pP, aa_in, bb_in, pp_in, time_decay, sA, sB, sP);
    scan_out<<<NCHUNK, 256, 0, stream>>>(kbuf, vbuf, rbuf, time_decay, time_first,
                                         sA, sB, sP, arwkv, aa_out, bb_out, pp_out);
    // d6: output GEMM + residual
    gemm_o<<<1024, 256, 0, stream>>>(arwkv, Wt + 3 * C2, out, x);
}

// Round 14
// 475.666 us; speedup vs baseline: 1.0116x; 1.0116x over previous
//
#include <hip/hip_runtime.h>
#include <stdint.h>

#define T_DIM 8192
#define C_DIM 2048
#define LCHUNK 32
#define NCHUNK (T_DIM / LCHUNK)   // 256

typedef unsigned short u16;
typedef __bf16 bf16x8_t __attribute__((ext_vector_type(8)));
typedef float f32x4_t __attribute__((ext_vector_type(4)));

__device__ __forceinline__ u16 f2bf(float f) {
    union { float f; uint32_t u; } x; x.f = f;
    uint32_t r = x.u + 0x7fffu + ((x.u >> 16) & 1u);
    return (u16)(r >> 16);
}
__device__ __forceinline__ float bf2f(u16 u) {
    union { uint32_t u; float f; } x; x.u = ((uint32_t)u) << 16;
    return x.f;
}
__device__ __forceinline__ void gload16(const void* g, void* l) {
    __builtin_amdgcn_global_load_lds((const __attribute__((address_space(1))) uint32_t*)g,
                                     (__attribute__((address_space(3))) uint32_t*)l, 16, 0, 0);
}
__device__ __forceinline__ f32x4_t mfma16(bf16x8_t a, bf16x8_t b, f32x4_t c) {
    return __builtin_amdgcn_mfma_f32_16x16x32_bf16(a, b, c, 0, 0, 0);
}

// ---- shared helper: 32x32 weight transpose tile: Wt[n][k] = bf16(W[k][n]) ----
__device__ __forceinline__ void transpose_tile(const float* __restrict__ W, u16* __restrict__ Tm,
                                               int bn, int bk, float* shf)
{
    const int tid = threadIdx.x;
    const int tx = tid & 31, ty = tid >> 5;
#pragma unroll
    for (int i = 0; i < 4; ++i)
        shf[(ty + 8 * i) * 33 + tx] = W[(size_t)(bk + ty + 8 * i) * C_DIM + bn + tx];
    __syncthreads();
#pragma unroll
    for (int i = 0; i < 4; ++i)
        Tm[(size_t)(bn + ty + 8 * i) * C_DIM + bk + tx] = f2bf(shf[tx * 33 + ty + 8 * i]);
}

// ---------------- prep: ln_mix (blocks 0..8191) U transpose Wk,Wv,Wr (blocks 8192..20479) --------
union F8 { float4 v[2]; float f[8]; };

__global__ __launch_bounds__(256)
void prep_kernel(const float* __restrict__ W0, const float* __restrict__ W1,
                 const float* __restrict__ W2, u16* __restrict__ Wt,
                 const float* __restrict__ x, const float* __restrict__ sx,
                 const float* __restrict__ lns, const float* __restrict__ lnb,
                 const float* __restrict__ tmk, const float* __restrict__ tmv,
                 const float* __restrict__ tmr,
                 u16* __restrict__ kx, u16* __restrict__ vx, u16* __restrict__ rx,
                 float* __restrict__ xx_last)
{
    __shared__ float shf[32 * 33];
    const int bid = blockIdx.x;
    const int tid = threadIdx.x;

    if (bid >= 8192) {
        const int z = (bid - 8192) >> 12;
        const int rem = (bid - 8192) & 4095;
        const float* W = (z == 0) ? W0 : (z == 1) ? W1 : W2;
        transpose_tile(W, Wt + (size_t)z * C_DIM * C_DIM, (rem & 63) * 32, (rem >> 6) * 32, shf);
        return;
    }

    const int t = bid;
    const size_t rowoff = (size_t)t * C_DIM;

    F8 a, p;
    const float4* xt = (const float4*)(x + rowoff);
    a.v[0] = xt[2 * tid]; a.v[1] = xt[2 * tid + 1];
    const float4* xp = (t == 0) ? (const float4*)sx : (const float4*)(x + rowoff - C_DIM);
    p.v[0] = xp[2 * tid]; p.v[1] = xp[2 * tid + 1];

    float s1 = 0.f, s2 = 0.f, s3 = 0.f, s4 = 0.f;
#pragma unroll
    for (int i = 0; i < 8; ++i) {
        s1 += a.f[i]; s2 += a.f[i] * a.f[i];
        s3 += p.f[i]; s4 += p.f[i] * p.f[i];
    }
#pragma unroll
    for (int off = 32; off; off >>= 1) {
        s1 += __shfl_down(s1, off);
        s2 += __shfl_down(s2, off);
        s3 += __shfl_down(s3, off);
        s4 += __shfl_down(s4, off);
    }
    float* red = shf;
    if ((tid & 63) == 0) {
        red[0 * 4 + (tid >> 6)] = s1; red[1 * 4 + (tid >> 6)] = s2;
        red[2 * 4 + (tid >> 6)] = s3; red[3 * 4 + (tid >> 6)] = s4;
    }
    __syncthreads();
    s1 = red[0] + red[1] + red[2] + red[3];
    s2 = red[4] + red[5] + red[6] + red[7];
    s3 = red[8] + red[9] + red[10] + red[11];
    s4 = red[12] + red[13] + red[14] + red[15];
    const float inv = 1.0f / (float)C_DIM;
    const float mu = s1 * inv;
    const float rstd = rsqrtf(s2 * inv - mu * mu + 1e-5f);
    const float mup = s3 * inv;
    const float rstdp = rsqrtf(s4 * inv - mup * mup + 1e-5f);

    F8 ls, lb, mk, mv, mr;
    { const float4* q = (const float4*)lns; ls.v[0] = q[2*tid]; ls.v[1] = q[2*tid+1]; }
    { const float4* q = (const float4*)lnb; lb.v[0] = q[2*tid]; lb.v[1] = q[2*tid+1]; }
    { const float4* q = (const float4*)tmk; mk.v[0] = q[2*tid]; mk.v[1] = q[2*tid+1]; }
    { const float4* q = (const float4*)tmv; mv.v[0] = q[2*tid]; mv.v[1] = q[2*tid+1]; }
    { const float4* q = (const float4*)tmr; mr.v[0] = q[2*tid]; mr.v[1] = q[2*tid+1]; }

    union { u16 u[8]; uint4 q; } ok, ov, orr;
#pragma unroll
    for (int i = 0; i < 8; ++i) {
        const float xxv  = (a.f[i] - mu) * rstd * ls.f[i] + lb.f[i];
        const float prev = (t == 0) ? p.f[i] : (p.f[i] - mup) * rstdp * ls.f[i] + lb.f[i];
        ok.u[i]  = f2bf(xxv * mk.f[i] + prev * (1.f - mk.f[i]));
        ov.u[i]  = f2bf(xxv * mv.f[i] + prev * (1.f - mv.f[i]));
        orr.u[i] = f2bf(xxv * mr.f[i] + prev * (1.f - mr.f[i]));
        if (t == T_DIM - 1) xx_last[tid * 8 + i] = xxv;
    }
    ((uint4*)(kx + rowoff))[tid] = ok.q;
    ((uint4*)(vx + rowoff))[tid] = ov.q;
    ((uint4*)(rx + rowoff))[tid] = orr.q;
}

// ---------------- dbuf GEMM core (r8-proven best: 37.8% MfmaUtil, 32 KiB, 4 blocks/CU) ----------
// mode 1: bf16 out, 2: sigmoid->bf16 out, 0: f32 out + resid
__device__ __forceinline__ void gemm_core_db(
    const u16* __restrict__ A, const u16* __restrict__ Bt,
    void* __restrict__ Cout, const float* __restrict__ resid,
    const int mode, const int N, const int K, const int m0, const int n0, u16* lds)
{
    const int tid = threadIdx.x;
    const int wave = tid >> 6, lane = tid & 63;
    const int wm = wave >> 1, wn = wave & 1;
    const int fr = lane & 15, fo = lane >> 4;
    const int sw = (fo ^ ((fr >> 1) & 3)) * 8;

    f32x4_t acc[4][4] = {};

    const int lrow = lane >> 2;
    const int scol = ((lane & 3) ^ ((lane >> 3) & 3)) * 8;
    const u16* gA = A  + (size_t)(m0 + wave * 16 + lrow) * K + scol;
    const u16* gB = Bt + (size_t)(n0 + wave * 16 + lrow) * K + scol;
    const size_t rk64 = (size_t)64 * K;
    const int dA = wave * 512;
    const int dB = 4096 + wave * 512;

    auto stage = [&](int t) {
        const int b = (t & 1) * 8192;
        const u16* ga = gA + (size_t)t * 32;
        const u16* gb = gB + (size_t)t * 32;
        gload16(ga,        lds + b + dA);
        gload16(ga + rk64, lds + b + dA + 2048);
        gload16(gb,        lds + b + dB);
        gload16(gb + rk64, lds + b + dB + 2048);
    };

    const int NT = K >> 5;
    stage(0);
    asm volatile("s_waitcnt vmcnt(0)" ::: "memory");
    asm volatile("s_barrier" ::: "memory");

    for (int t = 0; t < NT; ++t) {
        if (t + 1 < NT) stage(t + 1);
        const u16* lA = lds + (t & 1) * 8192 + (wm * 64 + fr) * 32;
        const u16* lB = lds + (t & 1) * 8192 + 4096 + (wn * 64 + fr) * 32;
        bf16x8_t a[4], b[4];
#pragma unroll
        for (int i = 0; i < 4; ++i) {
            a[i] = *(const bf16x8_t*)(lA + i * 512 + sw);
            b[i] = *(const bf16x8_t*)(lB + i * 512 + sw);
        }
        __builtin_amdgcn_s_setprio(1);
#pragma unroll
        for (int mi = 0; mi < 4; ++mi)
#pragma unroll
            for (int ni = 0; ni < 4; ++ni)
                acc[mi][ni] = mfma16(a[mi], b[ni], acc[mi][ni]);
        __builtin_amdgcn_s_setprio(0);
        asm volatile("s_waitcnt vmcnt(0)" ::: "memory");
        asm volatile("s_barrier" ::: "memory");
    }

    const int r4 = fo * 4;
#pragma unroll
    for (int mi = 0; mi < 4; ++mi) {
#pragma unroll
        for (int ni = 0; ni < 4; ++ni) {
            const int col = n0 + wn * 64 + ni * 16 + fr;
#pragma unroll
            for (int i = 0; i < 4; ++i) {
                const int row = m0 + wm * 64 + mi * 16 + r4 + i;
                float v = acc[mi][ni][i];
                if (mode == 0) {
                    ((float*)Cout)[(size_t)row * N + col] = v + resid[(size_t)row * N + col];
                } else if (mode == 1) {
                    ((u16*)Cout)[(size_t)row * N + col] = f2bf(v);
                } else {
                    const float s = 1.f / (1.f + __expf(-v));
                    ((u16*)Cout)[(size_t)row * N + col] = f2bf(s);
                }
            }
        }
    }
}

// k,v,r GEMMs (blocks 0..3071, dbuf core) U Wo transpose (blocks 3072..7167)
__global__ __launch_bounds__(256, 4)
void gemm_kvr(const u16* __restrict__ kx, const u16* __restrict__ vx, const u16* __restrict__ rxp,
              const float* __restrict__ Wo, u16* __restrict__ Wt,
              u16* __restrict__ kbuf, u16* __restrict__ vbuf, u16* __restrict__ rbuf)
{
    __shared__ u16 lds[16384];  // 32 KiB
    const int bid = blockIdx.x;
    if (bid >= 3072) {
        const int rem = bid - 3072;
        transpose_tile(Wo, Wt + (size_t)3 * C_DIM * C_DIM, (rem & 63) * 32, (rem >> 6) * 32,
                       (float*)lds);
        return;
    }
    const int which = bid >> 10;
    const int b = bid & 1023;
    const int m0 = (b & 63) << 7;           // m-fast: XCD round-robin shares B panel
    const int n0 = (b >> 6) << 7;
    const u16* A = (which == 0) ? kx : (which == 1) ? vx : rxp;
    const u16* B = Wt + (size_t)which * C_DIM * C_DIM;
    u16* C = (which == 0) ? kbuf : (which == 1) ? vbuf : rbuf;
    gemm_core_db(A, B, C, nullptr, (which == 2) ? 2 : 1, C_DIM, C_DIM, m0, n0, lds);
}

__global__ __launch_bounds__(256, 4)
void gemm_o(const u16* __restrict__ Aw, const u16* __restrict__ Wt3,
            float* __restrict__ out, const float* __restrict__ x)
{
    __shared__ u16 lds[16384];
    const int m0 = (int)(blockIdx.x & 63) << 7;
    const int n0 = (int)(blockIdx.x >> 6) << 7;
    gemm_core_db(Aw, Wt3, out, x, 0, C_DIM, C_DIM, m0, n0, lds);
}

// ---------------- WKV scan, chunked, 8 channels/thread (vectorized uint4 loads) ----------------
// LCHUNK=32, NCHUNK=256: grid 256 blocks x 256 threads; thread handles channels c0..c0+7.
__global__ __launch_bounds__(256)
void scan_partial(const u16* __restrict__ k, const u16* __restrict__ v,
                  const float* __restrict__ time_decay,
                  float* __restrict__ pA, float* __restrict__ pB, float* __restrict__ pP)
{
    const int j = blockIdx.x;
    const int c0 = threadIdx.x * 8;
    float w8[8];
    {
        F8 t; const float4* q = (const float4*)(time_decay + c0);
        t.v[0] = q[0]; t.v[1] = q[1];
#pragma unroll
        for (int i = 0; i < 8; ++i) w8[i] = -__expf(t.f[i]);
    }
    float aa[8] = {}, bb[8] = {}, pp[8];
#pragma unroll
    for (int i = 0; i < 8; ++i) pp[i] = -1e30f;

    const u16* kp = k + (size_t)j * LCHUNK * C_DIM + c0;
    const u16* vp = v + (size_t)j * LCHUNK * C_DIM + c0;
    for (int s = 0; s < LCHUNK; ++s) {
        union { uint4 q; u16 u[8]; } kq, vq;
        kq.q = *(const uint4*)kp; vq.q = *(const uint4*)vp;
        kp += C_DIM; vp += C_DIM;
#pragma unroll
        for (int i = 0; i < 8; ++i) {
            const float kk = bf2f(kq.u[i]);
            const float vv = bf2f(vq.u[i]);
            const float ww = w8[i] + pp[i];
            const float p2 = fmaxf(ww, kk);
            const float e1 = __expf(ww - p2);
            const float e2 = __expf(kk - p2);
            aa[i] = e1 * aa[i] + e2 * vv;
            bb[i] = e1 * bb[i] + e2;
            pp[i] = p2;
        }
    }
    const int o = j * C_DIM + c0;
    *(float4*)(pA + o)     = make_float4(aa[0], aa[1], aa[2], aa[3]);
    *(float4*)(pA + o + 4) = make_float4(aa[4], aa[5], aa[6], aa[7]);
    *(float4*)(pB + o)     = make_float4(bb[0], bb[1], bb[2], bb[3]);
    *(float4*)(pB + o + 4) = make_float4(bb[4], bb[5], bb[6], bb[7]);
    *(float4*)(pP + o)     = make_float4(pp[0], pp[1], pp[2], pp[3]);
    *(float4*)(pP + o + 4) = make_float4(pp[4], pp[5], pp[6], pp[7]);
}

// sequential cross-chunk combine, 8-deep software prefetch (statically indexed regs).
// Per 8-iteration group, next group's partials are loaded BEFORE the dependent chain runs:
// ~320 cyc of chain covers most of the cross-XCD L2/HBM latency (r13 lesson: 1-deep = +30us).
__global__ __launch_bounds__(256)
void scan_combine(const float* __restrict__ pA, const float* __restrict__ pB,
                  const float* __restrict__ pP,
                  const float* __restrict__ aa_in, const float* __restrict__ bb_in,
                  const float* __restrict__ pp_in,
                  const float* __restrict__ time_decay,
                  float* __restrict__ sA, float* __restrict__ sB, float* __restrict__ sP)
{
    const int c = blockIdx.x * 256 + threadIdx.x;
    const float wL = -__expf(time_decay[c]) * (float)LCHUNK;
    float a = aa_in[c], b = bb_in[c], p = pp_in[c];
    float Ab[8], Bb[8], Pb[8];
#pragma unroll
    for (int i = 0; i < 8; ++i) {
        const int o = i * C_DIM + c;
        Ab[i] = pA[o]; Bb[i] = pB[o]; Pb[i] = pP[o];
    }
    for (int j0 = 0; j0 < NCHUNK; j0 += 8) {
        float An[8], Bn[8], Pn[8];
        if (j0 + 8 < NCHUNK) {
#pragma unroll
            for (int i = 0; i < 8; ++i) {
                const int o = (j0 + 8 + i) * C_DIM + c;
                An[i] = pA[o]; Bn[i] = pB[o]; Pn[i] = pP[o];
            }
        } else {
#pragma unroll
            for (int i = 0; i < 8; ++i) { An[i] = 0.f; Bn[i] = 0.f; Pn[i] = 0.f; }
        }
#pragma unroll
        for (int i = 0; i < 8; ++i) {
            const int o = (j0 + i) * C_DIM + c;
            sA[o] = a; sB[o] = b; sP[o] = p;
            const float pd = p + wL;
            const float q = fmaxf(pd, Pb[i]);
            const float e1 = __expf(pd - q), e2 = __expf(Pb[i] - q);
            a = e1 * a + e2 * Ab[i];
            b = e1 * b + e2 * Bb[i];
            p = q;
        }
#pragma unroll
        for (int i = 0; i < 8; ++i) { Ab[i] = An[i]; Bb[i] = Bn[i]; Pb[i] = Pn[i]; }
    }
}

__global__ __launch_bounds__(256)
void scan_out(const u16* __restrict__ k, const u16* __restrict__ v,
              const u16* __restrict__ r,
              const float* __restrict__ time_decay, const float* __restrict__ time_first,
              const float* __restrict__ sA, const float* __restrict__ sB,
              const float* __restrict__ sP,
              u16* __restrict__ arwkv,
              float* __restrict__ aa_out, float* __restrict__ bb_out, float* __restrict__ pp_out)
{
    const int j = blockIdx.x;
    const int c0 = threadIdx.x * 8;
    float w8[8], u8[8];
    {
        F8 t; const float4* q = (const float4*)(time_decay + c0);
        t.v[0] = q[0]; t.v[1] = q[1];
#pragma unroll
        for (int i = 0; i < 8; ++i) w8[i] = -__expf(t.f[i]);
        const float4* q2 = (const float4*)(time_first + c0);
        t.v[0] = q2[0]; t.v[1] = q2[1];
#pragma unroll
        for (int i = 0; i < 8; ++i) u8[i] = t.f[i];
    }
    float aa[8], bb[8], pp[8];
    {
        const int so = j * C_DIM + c0;
        F8 t;
        t.v[0] = ((const float4*)(sA + so))[0]; t.v[1] = ((const float4*)(sA + so))[1];
#pragma unroll
        for (int i = 0; i < 8; ++i) aa[i] = t.f[i];
        t.v[0] = ((const float4*)(sB + so))[0]; t.v[1] = ((const float4*)(sB + so))[1];
#pragma unroll
        for (int i = 0; i < 8; ++i) bb[i] = t.f[i];
        t.v[0] = ((const float4*)(sP + so))[0]; t.v[1] = ((const float4*)(sP + so))[1];
#pragma unroll
        for (int i = 0; i < 8; ++i) pp[i] = t.f[i];
    }

    const size_t base = (size_t)j * LCHUNK * C_DIM + c0;
    const u16* kp = k + base;
    const u16* vp = v + base;
    const u16* rp = r + base;
    u16* op = arwkv + base;
    for (int s = 0; s < LCHUNK; ++s) {
        union { uint4 q; u16 u[8]; } kq, vq, rq, oq;
        kq.q = *(const uint4*)kp; vq.q = *(const uint4*)vp; rq.q = *(const uint4*)rp;
        kp += C_DIM; vp += C_DIM; rp += C_DIM;
#pragma unroll
        for (int i = 0; i < 8; ++i) {
            const float kk = bf2f(kq.u[i]);
            const float vv = bf2f(vq.u[i]);
            const float sr = bf2f(rq.u[i]);
            const float ww = u8[i] + kk;
            const float p = fmaxf(pp[i], ww);
            const float e1 = __expf(pp[i] - p);
            const float e2 = __expf(ww - p);
            const float o = (e1 * aa[i] + e2 * vv) / (e1 * bb[i] + e2);
            oq.u[i] = f2bf(sr * o);
            const float ww2 = w8[i] + pp[i];
            const float p2 = fmaxf(ww2, kk);
            const float f1 = __expf(ww2 - p2);
            const float f2 = __expf(kk - p2);
            aa[i] = f1 * aa[i] + f2 * vv;
            bb[i] = f1 * bb[i] + f2;
            pp[i] = p2;
        }
        *(uint4*)op = oq.q;
        op += C_DIM;
    }
    if (j == NCHUNK - 1) {
#pragma unroll
        for (int i = 0; i < 8; ++i) {
            aa_out[c0 + i] = aa[i]; bb_out[c0 + i] = bb[i]; pp_out[c0 + i] = pp[i];
        }
    }
}

// ---------------- launcher ----------------
extern "C" void kernel_launch(void* const* d_in, const int* in_sizes, int n_in,
                              void* d_out, int out_size, void* d_ws, size_t ws_size,
                              hipStream_t stream)
{
    (void)in_sizes; (void)n_in; (void)out_size; (void)ws_size;
    const float* x          = (const float*)d_in[0];
    const float* sx         = (const float*)d_in[1];
    const float* aa_in      = (const float*)d_in[2];
    const float* bb_in      = (const float*)d_in[3];
    const float* pp_in      = (const float*)d_in[4];
    const float* time_first = (const float*)d_in[5];
    const float* time_decay = (const float*)d_in[6];
    const float* tmk        = (const float*)d_in[7];
    const float* tmv        = (const float*)d_in[8];
    const float* tmr        = (const float*)d_in[9];
    const float* lns        = (const float*)d_in[10];
    const float* lnb        = (const float*)d_in[11];
    const float* Wk         = (const float*)d_in[12];
    const float* Wv         = (const float*)d_in[13];
    const float* Wr         = (const float*)d_in[14];
    const float* Wo         = (const float*)d_in[15];

    float* out     = (float*)d_out;
    float* xx_last = out + (size_t)T_DIM * C_DIM;
    float* aa_out  = xx_last + C_DIM;
    float* bb_out  = aa_out + C_DIM;
    float* pp_out  = bb_out + C_DIM;

    const size_t TC = (size_t)T_DIM * C_DIM;
    const size_t C2 = (size_t)C_DIM * C_DIM;
    u16* kx    = (u16*)d_ws;
    u16* vx    = kx + TC;
    u16* rx    = vx + TC;
    u16* Wt    = rx + TC;                  // 4*C2 bf16
    u16* kbuf  = Wt + 4 * C2;              // TC bf16
    u16* vbuf  = kbuf + TC;                // TC bf16
    u16* rbuf  = vbuf + TC;                // TC bf16
    float* pA  = (float*)(rbuf + TC);      // NCHUNK*C f32 each
    float* pB  = pA + (size_t)NCHUNK * C_DIM;
    float* pP  = pB + (size_t)NCHUNK * C_DIM;
    float* sA  = pP + (size_t)NCHUNK * C_DIM;
    float* sB  = sA + (size_t)NCHUNK * C_DIM;
    float* sP  = sB + (size_t)NCHUNK * C_DIM;
    u16* arwkv = rx;   // alias: rx dead after gemm_kvr

    // d1: ln_mix U transpose Wk,Wv,Wr
    prep_kernel<<<8192 + 12288, 256, 0, stream>>>(Wk, Wv, Wr, Wt,
                                                  x, sx, lns, lnb, tmk, tmv, tmr,
                                                  kx, vx, rx, xx_last);
    // d2: k,v,r GEMMs (dbuf core, 4 blocks/CU) U Wo transpose
    gemm_kvr<<<3072 + 4096, 256, 0, stream>>>(kx, vx, rx, Wo, Wt, kbuf, vbuf, rbuf);
    // d3-d5: chunked WKV scan (8 channels/thread, vectorized; 8-deep-prefetch combine)
    scan_partial<<<NCHUNK, 256, 0, stream>>>(kbuf, vbuf, time_decay, pA, pB, pP);
    scan_combine<<<C_DIM / 256, 256, 0, stream>>>(pA, pB, pP, aa_in, bb_in, pp_in, time_decay, sA, sB, sP);
    scan_out<<<NCHUNK, 256, 0, stream>>>(kbuf, vbuf, rbuf, time_decay, time_first,
                                         sA, sB, sP, arwkv, aa_out, bb_out, pp_out);
    // d6: output GEMM + residual
    gemm_o<<<1024, 256, 0, stream>>>(arwkv, Wt + 3 * C2, out, x);
}

// Round 15
// 463.641 us; speedup vs baseline: 1.0378x; 1.0259x over previous
//
#include <hip/hip_runtime.h>
#include <stdint.h>

#define T_DIM 8192
#define C_DIM 2048
#define LCHUNK 64
#define NCHUNK (T_DIM / LCHUNK)   // 128

typedef unsigned short u16;
typedef __bf16 bf16x8_t __attribute__((ext_vector_type(8)));
typedef float f32x4_t __attribute__((ext_vector_type(4)));

__device__ __forceinline__ u16 f2bf(float f) {
    union { float f; uint32_t u; } x; x.f = f;
    uint32_t r = x.u + 0x7fffu + ((x.u >> 16) & 1u);
    return (u16)(r >> 16);
}
__device__ __forceinline__ float bf2f(u16 u) {
    union { uint32_t u; float f; } x; x.u = ((uint32_t)u) << 16;
    return x.f;
}
__device__ __forceinline__ void gload16(const void* g, void* l) {
    __builtin_amdgcn_global_load_lds((const __attribute__((address_space(1))) uint32_t*)g,
                                     (__attribute__((address_space(3))) uint32_t*)l, 16, 0, 0);
}
__device__ __forceinline__ f32x4_t mfma16(bf16x8_t a, bf16x8_t b, f32x4_t c) {
    return __builtin_amdgcn_mfma_f32_16x16x32_bf16(a, b, c, 0, 0, 0);
}

// ---- shared helper: 32x32 weight transpose tile: Wt[n][k] = bf16(W[k][n]) ----
__device__ __forceinline__ void transpose_tile(const float* __restrict__ W, u16* __restrict__ Tm,
                                               int bn, int bk, float* shf)
{
    const int tid = threadIdx.x;
    const int tx = tid & 31, ty = tid >> 5;
#pragma unroll
    for (int i = 0; i < 4; ++i)
        shf[(ty + 8 * i) * 33 + tx] = W[(size_t)(bk + ty + 8 * i) * C_DIM + bn + tx];
    __syncthreads();
#pragma unroll
    for (int i = 0; i < 4; ++i)
        Tm[(size_t)(bn + ty + 8 * i) * C_DIM + bk + tx] = f2bf(shf[tx * 33 + ty + 8 * i]);
}

// ---------------- prep: ln_mix (blocks 0..8191) U transpose Wk,Wv,Wr (blocks 8192..20479) --------
union F8 { float4 v[2]; float f[8]; };

__global__ __launch_bounds__(256)
void prep_kernel(const float* __restrict__ W0, const float* __restrict__ W1,
                 const float* __restrict__ W2, u16* __restrict__ Wt,
                 const float* __restrict__ x, const float* __restrict__ sx,
                 const float* __restrict__ lns, const float* __restrict__ lnb,
                 const float* __restrict__ tmk, const float* __restrict__ tmv,
                 const float* __restrict__ tmr,
                 u16* __restrict__ kx, u16* __restrict__ vx, u16* __restrict__ rx,
                 float* __restrict__ xx_last)
{
    __shared__ float shf[32 * 33];
    const int bid = blockIdx.x;
    const int tid = threadIdx.x;

    if (bid >= 8192) {
        const int z = (bid - 8192) >> 12;
        const int rem = (bid - 8192) & 4095;
        const float* W = (z == 0) ? W0 : (z == 1) ? W1 : W2;
        transpose_tile(W, Wt + (size_t)z * C_DIM * C_DIM, (rem & 63) * 32, (rem >> 6) * 32, shf);
        return;
    }

    const int t = bid;
    const size_t rowoff = (size_t)t * C_DIM;

    F8 a, p;
    const float4* xt = (const float4*)(x + rowoff);
    a.v[0] = xt[2 * tid]; a.v[1] = xt[2 * tid + 1];
    const float4* xp = (t == 0) ? (const float4*)sx : (const float4*)(x + rowoff - C_DIM);
    p.v[0] = xp[2 * tid]; p.v[1] = xp[2 * tid + 1];

    float s1 = 0.f, s2 = 0.f, s3 = 0.f, s4 = 0.f;
#pragma unroll
    for (int i = 0; i < 8; ++i) {
        s1 += a.f[i]; s2 += a.f[i] * a.f[i];
        s3 += p.f[i]; s4 += p.f[i] * p.f[i];
    }
#pragma unroll
    for (int off = 32; off; off >>= 1) {
        s1 += __shfl_down(s1, off);
        s2 += __shfl_down(s2, off);
        s3 += __shfl_down(s3, off);
        s4 += __shfl_down(s4, off);
    }
    float* red = shf;
    if ((tid & 63) == 0) {
        red[0 * 4 + (tid >> 6)] = s1; red[1 * 4 + (tid >> 6)] = s2;
        red[2 * 4 + (tid >> 6)] = s3; red[3 * 4 + (tid >> 6)] = s4;
    }
    __syncthreads();
    s1 = red[0] + red[1] + red[2] + red[3];
    s2 = red[4] + red[5] + red[6] + red[7];
    s3 = red[8] + red[9] + red[10] + red[11];
    s4 = red[12] + red[13] + red[14] + red[15];
    const float inv = 1.0f / (float)C_DIM;
    const float mu = s1 * inv;
    const float rstd = rsqrtf(s2 * inv - mu * mu + 1e-5f);
    const float mup = s3 * inv;
    const float rstdp = rsqrtf(s4 * inv - mup * mup + 1e-5f);

    F8 ls, lb, mk, mv, mr;
    { const float4* q = (const float4*)lns; ls.v[0] = q[2*tid]; ls.v[1] = q[2*tid+1]; }
    { const float4* q = (const float4*)lnb; lb.v[0] = q[2*tid]; lb.v[1] = q[2*tid+1]; }
    { const float4* q = (const float4*)tmk; mk.v[0] = q[2*tid]; mk.v[1] = q[2*tid+1]; }
    { const float4* q = (const float4*)tmv; mv.v[0] = q[2*tid]; mv.v[1] = q[2*tid+1]; }
    { const float4* q = (const float4*)tmr; mr.v[0] = q[2*tid]; mr.v[1] = q[2*tid+1]; }

    union { u16 u[8]; uint4 q; } ok, ov, orr;
#pragma unroll
    for (int i = 0; i < 8; ++i) {
        const float xxv  = (a.f[i] - mu) * rstd * ls.f[i] + lb.f[i];
        const float prev = (t == 0) ? p.f[i] : (p.f[i] - mup) * rstdp * ls.f[i] + lb.f[i];
        ok.u[i]  = f2bf(xxv * mk.f[i] + prev * (1.f - mk.f[i]));
        ov.u[i]  = f2bf(xxv * mv.f[i] + prev * (1.f - mv.f[i]));
        orr.u[i] = f2bf(xxv * mr.f[i] + prev * (1.f - mr.f[i]));
        if (t == T_DIM - 1) xx_last[tid * 8 + i] = xxv;
    }
    ((uint4*)(kx + rowoff))[tid] = ok.q;
    ((uint4*)(vx + rowoff))[tid] = ov.q;
    ((uint4*)(rx + rowoff))[tid] = orr.q;
}

// ---------------- dbuf GEMM core (r8-proven best: 37.8% MfmaUtil, 32 KiB, 4 blocks/CU) ----------
// mode 1: bf16 out, 2: sigmoid->bf16 out, 0: f32 out + resid
__device__ __forceinline__ void gemm_core_db(
    const u16* __restrict__ A, const u16* __restrict__ Bt,
    void* __restrict__ Cout, const float* __restrict__ resid,
    const int mode, const int N, const int K, const int m0, const int n0, u16* lds)
{
    const int tid = threadIdx.x;
    const int wave = tid >> 6, lane = tid & 63;
    const int wm = wave >> 1, wn = wave & 1;
    const int fr = lane & 15, fo = lane >> 4;
    const int sw = (fo ^ ((fr >> 1) & 3)) * 8;

    f32x4_t acc[4][4] = {};

    const int lrow = lane >> 2;
    const int scol = ((lane & 3) ^ ((lane >> 3) & 3)) * 8;
    const u16* gA = A  + (size_t)(m0 + wave * 16 + lrow) * K + scol;
    const u16* gB = Bt + (size_t)(n0 + wave * 16 + lrow) * K + scol;
    const size_t rk64 = (size_t)64 * K;
    const int dA = wave * 512;
    const int dB = 4096 + wave * 512;

    auto stage = [&](int t) {
        const int b = (t & 1) * 8192;
        const u16* ga = gA + (size_t)t * 32;
        const u16* gb = gB + (size_t)t * 32;
        gload16(ga,        lds + b + dA);
        gload16(ga + rk64, lds + b + dA + 2048);
        gload16(gb,        lds + b + dB);
        gload16(gb + rk64, lds + b + dB + 2048);
    };

    const int NT = K >> 5;
    stage(0);
    asm volatile("s_waitcnt vmcnt(0)" ::: "memory");
    asm volatile("s_barrier" ::: "memory");

    for (int t = 0; t < NT; ++t) {
        if (t + 1 < NT) stage(t + 1);
        const u16* lA = lds + (t & 1) * 8192 + (wm * 64 + fr) * 32;
        const u16* lB = lds + (t & 1) * 8192 + 4096 + (wn * 64 + fr) * 32;
        bf16x8_t a[4], b[4];
#pragma unroll
        for (int i = 0; i < 4; ++i) {
            a[i] = *(const bf16x8_t*)(lA + i * 512 + sw);
            b[i] = *(const bf16x8_t*)(lB + i * 512 + sw);
        }
        __builtin_amdgcn_s_setprio(1);
#pragma unroll
        for (int mi = 0; mi < 4; ++mi)
#pragma unroll
            for (int ni = 0; ni < 4; ++ni)
                acc[mi][ni] = mfma16(a[mi], b[ni], acc[mi][ni]);
        __builtin_amdgcn_s_setprio(0);
        asm volatile("s_waitcnt vmcnt(0)" ::: "memory");
        asm volatile("s_barrier" ::: "memory");
    }

    const int r4 = fo * 4;
#pragma unroll
    for (int mi = 0; mi < 4; ++mi) {
#pragma unroll
        for (int ni = 0; ni < 4; ++ni) {
            const int col = n0 + wn * 64 + ni * 16 + fr;
#pragma unroll
            for (int i = 0; i < 4; ++i) {
                const int row = m0 + wm * 64 + mi * 16 + r4 + i;
                float v = acc[mi][ni][i];
                if (mode == 0) {
                    ((float*)Cout)[(size_t)row * N + col] = v + resid[(size_t)row * N + col];
                } else if (mode == 1) {
                    ((u16*)Cout)[(size_t)row * N + col] = f2bf(v);
                } else {
                    const float s = 1.f / (1.f + __expf(-v));
                    ((u16*)Cout)[(size_t)row * N + col] = f2bf(s);
                }
            }
        }
    }
}

// k,v,r GEMMs (blocks 0..3071, dbuf core) U Wo transpose (blocks 3072..7167)
__global__ __launch_bounds__(256, 4)
void gemm_kvr(const u16* __restrict__ kx, const u16* __restrict__ vx, const u16* __restrict__ rxp,
              const float* __restrict__ Wo, u16* __restrict__ Wt,
              u16* __restrict__ kbuf, u16* __restrict__ vbuf, u16* __restrict__ rbuf)
{
    __shared__ u16 lds[16384];  // 32 KiB
    const int bid = blockIdx.x;
    if (bid >= 3072) {
        const int rem = bid - 3072;
        transpose_tile(Wo, Wt + (size_t)3 * C_DIM * C_DIM, (rem & 63) * 32, (rem >> 6) * 32,
                       (float*)lds);
        return;
    }
    const int which = bid >> 10;
    const int b = bid & 1023;
    const int m0 = (b & 63) << 7;           // m-fast: XCD round-robin shares B panel
    const int n0 = (b >> 6) << 7;
    const u16* A = (which == 0) ? kx : (which == 1) ? vx : rxp;
    const u16* B = Wt + (size_t)which * C_DIM * C_DIM;
    u16* C = (which == 0) ? kbuf : (which == 1) ? vbuf : rbuf;
    gemm_core_db(A, B, C, nullptr, (which == 2) ? 2 : 1, C_DIM, C_DIM, m0, n0, lds);
}

__global__ __launch_bounds__(256, 4)
void gemm_o(const u16* __restrict__ Aw, const u16* __restrict__ Wt3,
            float* __restrict__ out, const float* __restrict__ x)
{
    __shared__ u16 lds[16384];
    const int m0 = (int)(blockIdx.x & 63) << 7;
    const int n0 = (int)(blockIdx.x >> 6) << 7;
    gemm_core_db(Aw, Wt3, out, x, 0, C_DIM, C_DIM, m0, n0, lds);
}

// ---------------- WKV scan, chunked, 2 channels/thread (4B packed loads, 2-way ILP) -------------
// LCHUNK=64, NCHUNK=128: grid (128, 4) = 512 blocks = 2 blocks/CU (r11's proven occupancy)
// with 2x the load width of the scalar version.
__global__ __launch_bounds__(256)
void scan_partial(const u16* __restrict__ k, const u16* __restrict__ v,
                  const float* __restrict__ time_decay,
                  float* __restrict__ pA, float* __restrict__ pB, float* __restrict__ pP)
{
    const int j = blockIdx.x;
    const int c0 = blockIdx.y * 512 + threadIdx.x * 2;
    const float2 td = *(const float2*)(time_decay + c0);
    const float w0 = -__expf(td.x), w1 = -__expf(td.y);
    float aa0 = 0.f, bb0 = 0.f, pp0 = -1e30f;
    float aa1 = 0.f, bb1 = 0.f, pp1 = -1e30f;

    const u16* kp = k + (size_t)j * LCHUNK * C_DIM + c0;
    const u16* vp = v + (size_t)j * LCHUNK * C_DIM + c0;
    for (int s = 0; s < LCHUNK; ++s) {
        const uint32_t kq = *(const uint32_t*)kp;
        const uint32_t vq = *(const uint32_t*)vp;
        kp += C_DIM; vp += C_DIM;
        {
            const float kk = bf2f((u16)kq), vv = bf2f((u16)vq);
            const float ww = w0 + pp0;
            const float p2 = fmaxf(ww, kk);
            const float e1 = __expf(ww - p2), e2 = __expf(kk - p2);
            aa0 = e1 * aa0 + e2 * vv; bb0 = e1 * bb0 + e2; pp0 = p2;
        }
        {
            const float kk = bf2f((u16)(kq >> 16)), vv = bf2f((u16)(vq >> 16));
            const float ww = w1 + pp1;
            const float p2 = fmaxf(ww, kk);
            const float e1 = __expf(ww - p2), e2 = __expf(kk - p2);
            aa1 = e1 * aa1 + e2 * vv; bb1 = e1 * bb1 + e2; pp1 = p2;
        }
    }
    const int o = j * C_DIM + c0;
    *(float2*)(pA + o) = make_float2(aa0, aa1);
    *(float2*)(pB + o) = make_float2(bb0, bb1);
    *(float2*)(pP + o) = make_float2(pp0, pp1);
}

// sequential cross-chunk combine, 8-deep software prefetch (statically indexed regs).
__global__ __launch_bounds__(256)
void scan_combine(const float* __restrict__ pA, const float* __restrict__ pB,
                  const float* __restrict__ pP,
                  const float* __restrict__ aa_in, const float* __restrict__ bb_in,
                  const float* __restrict__ pp_in,
                  const float* __restrict__ time_decay,
                  float* __restrict__ sA, float* __restrict__ sB, float* __restrict__ sP)
{
    const int c = blockIdx.x * 256 + threadIdx.x;
    const float wL = -__expf(time_decay[c]) * (float)LCHUNK;
    float a = aa_in[c], b = bb_in[c], p = pp_in[c];
    float Ab[8], Bb[8], Pb[8];
#pragma unroll
    for (int i = 0; i < 8; ++i) {
        const int o = i * C_DIM + c;
        Ab[i] = pA[o]; Bb[i] = pB[o]; Pb[i] = pP[o];
    }
    for (int j0 = 0; j0 < NCHUNK; j0 += 8) {
        float An[8], Bn[8], Pn[8];
        if (j0 + 8 < NCHUNK) {
#pragma unroll
            for (int i = 0; i < 8; ++i) {
                const int o = (j0 + 8 + i) * C_DIM + c;
                An[i] = pA[o]; Bn[i] = pB[o]; Pn[i] = pP[o];
            }
        } else {
#pragma unroll
            for (int i = 0; i < 8; ++i) { An[i] = 0.f; Bn[i] = 0.f; Pn[i] = 0.f; }
        }
#pragma unroll
        for (int i = 0; i < 8; ++i) {
            const int o = (j0 + i) * C_DIM + c;
            sA[o] = a; sB[o] = b; sP[o] = p;
            const float pd = p + wL;
            const float q = fmaxf(pd, Pb[i]);
            const float e1 = __expf(pd - q), e2 = __expf(Pb[i] - q);
            a = e1 * a + e2 * Ab[i];
            b = e1 * b + e2 * Bb[i];
            p = q;
        }
#pragma unroll
        for (int i = 0; i < 8; ++i) { Ab[i] = An[i]; Bb[i] = Bn[i]; Pb[i] = Pn[i]; }
    }
}

__global__ __launch_bounds__(256)
void scan_out(const u16* __restrict__ k, const u16* __restrict__ v,
              const u16* __restrict__ r,
              const float* __restrict__ time_decay, const float* __restrict__ time_first,
              const float* __restrict__ sA, const float* __restrict__ sB,
              const float* __restrict__ sP,
              u16* __restrict__ arwkv,
              float* __restrict__ aa_out, float* __restrict__ bb_out, float* __restrict__ pp_out)
{
    const int j = blockIdx.x;
    const int c0 = blockIdx.y * 512 + threadIdx.x * 2;
    const float2 td = *(const float2*)(time_decay + c0);
    const float2 tf = *(const float2*)(time_first + c0);
    const float w0 = -__expf(td.x), w1 = -__expf(td.y);
    const float u0 = tf.x, u1 = tf.y;

    const int so = j * C_DIM + c0;
    float2 a2 = *(const float2*)(sA + so);
    float2 b2 = *(const float2*)(sB + so);
    float2 p2v = *(const float2*)(sP + so);
    float aa0 = a2.x, aa1 = a2.y, bb0 = b2.x, bb1 = b2.y, pp0 = p2v.x, pp1 = p2v.y;

    const size_t base = (size_t)j * LCHUNK * C_DIM + c0;
    const u16* kp = k + base;
    const u16* vp = v + base;
    const u16* rp = r + base;
    u16* op = arwkv + base;
    for (int s = 0; s < LCHUNK; ++s) {
        const uint32_t kq = *(const uint32_t*)kp;
        const uint32_t vq = *(const uint32_t*)vp;
        const uint32_t rq = *(const uint32_t*)rp;
        kp += C_DIM; vp += C_DIM; rp += C_DIM;
        uint32_t oq;
        {
            const float kk = bf2f((u16)kq), vv = bf2f((u16)vq), sr = bf2f((u16)rq);
            const float ww = u0 + kk;
            const float p = fmaxf(pp0, ww);
            const float e1 = __expf(pp0 - p), e2 = __expf(ww - p);
            const float o = (e1 * aa0 + e2 * vv) / (e1 * bb0 + e2);
            oq = (uint32_t)f2bf(sr * o);
            const float ww2 = w0 + pp0;
            const float q = fmaxf(ww2, kk);
            const float f1 = __expf(ww2 - q), f2v = __expf(kk - q);
            aa0 = f1 * aa0 + f2v * vv; bb0 = f1 * bb0 + f2v; pp0 = q;
        }
        {
            const float kk = bf2f((u16)(kq >> 16)), vv = bf2f((u16)(vq >> 16)), sr = bf2f((u16)(rq >> 16));
            const float ww = u1 + kk;
            const float p = fmaxf(pp1, ww);
            const float e1 = __expf(pp1 - p), e2 = __expf(ww - p);
            const float o = (e1 * aa1 + e2 * vv) / (e1 * bb1 + e2);
            oq |= ((uint32_t)f2bf(sr * o)) << 16;
            const float ww2 = w1 + pp1;
            const float q = fmaxf(ww2, kk);
            const float f1 = __expf(ww2 - q), f2v = __expf(kk - q);
            aa1 = f1 * aa1 + f2v * vv; bb1 = f1 * bb1 + f2v; pp1 = q;
        }
        *(uint32_t*)op = oq;
        op += C_DIM;
    }
    if (j == NCHUNK - 1) {
        aa_out[c0] = aa0; aa_out[c0 + 1] = aa1;
        bb_out[c0] = bb0; bb_out[c0 + 1] = bb1;
        pp_out[c0] = pp0; pp_out[c0 + 1] = pp1;
    }
}

// ---------------- launcher ----------------
extern "C" void kernel_launch(void* const* d_in, const int* in_sizes, int n_in,
                              void* d_out, int out_size, void* d_ws, size_t ws_size,
                              hipStream_t stream)
{
    (void)in_sizes; (void)n_in; (void)out_size; (void)ws_size;
    const float* x          = (const float*)d_in[0];
    const float* sx         = (const float*)d_in[1];
    const float* aa_in      = (const float*)d_in[2];
    const float* bb_in      = (const float*)d_in[3];
    const float* pp_in      = (const float*)d_in[4];
    const float* time_first = (const float*)d_in[5];
    const float* time_decay = (const float*)d_in[6];
    const float* tmk        = (const float*)d_in[7];
    const float* tmv        = (const float*)d_in[8];
    const float* tmr        = (const float*)d_in[9];
    const float* lns        = (const float*)d_in[10];
    const float* lnb        = (const float*)d_in[11];
    const float* Wk         = (const float*)d_in[12];
    const float* Wv         = (const float*)d_in[13];
    const float* Wr         = (const float*)d_in[14];
    const float* Wo         = (const float*)d_in[15];

    float* out     = (float*)d_out;
    float* xx_last = out + (size_t)T_DIM * C_DIM;
    float* aa_out  = xx_last + C_DIM;
    float* bb_out  = aa_out + C_DIM;
    float* pp_out  = bb_out + C_DIM;

    const size_t TC = (size_t)T_DIM * C_DIM;
    const size_t C2 = (size_t)C_DIM * C_DIM;
    u16* kx    = (u16*)d_ws;
    u16* vx    = kx + TC;
    u16* rx    = vx + TC;
    u16* Wt    = rx + TC;                  // 4*C2 bf16
    u16* kbuf  = Wt + 4 * C2;              // TC bf16
    u16* vbuf  = kbuf + TC;                // TC bf16
    u16* rbuf  = vbuf + TC;                // TC bf16
    float* pA  = (float*)(rbuf + TC);      // NCHUNK*C f32 each
    float* pB  = pA + (size_t)NCHUNK * C_DIM;
    float* pP  = pB + (size_t)NCHUNK * C_DIM;
    float* sA  = pP + (size_t)NCHUNK * C_DIM;
    float* sB  = sA + (size_t)NCHUNK * C_DIM;
    float* sP  = sB + (size_t)NCHUNK * C_DIM;
    u16* arwkv = rx;   // alias: rx dead after gemm_kvr

    // d1: ln_mix U transpose Wk,Wv,Wr
    prep_kernel<<<8192 + 12288, 256, 0, stream>>>(Wk, Wv, Wr, Wt,
                                                  x, sx, lns, lnb, tmk, tmv, tmr,
                                                  kx, vx, rx, xx_last);
    // d2: k,v,r GEMMs (dbuf core, 4 blocks/CU) U Wo transpose
    gemm_kvr<<<3072 + 4096, 256, 0, stream>>>(kx, vx, rx, Wo, Wt, kbuf, vbuf, rbuf);
    // d3-d5: chunked WKV scan (2 ch/thread, 512 blocks; 8-deep-prefetch combine)
    scan_partial<<<dim3(NCHUNK, 4), 256, 0, stream>>>(kbuf, vbuf, time_decay, pA, pB, pP);
    scan_combine<<<C_DIM / 256, 256, 0, stream>>>(pA, pB, pP, aa_in, bb_in, pp_in, time_decay, sA, sB, sP);
    scan_out<<<dim3(NCHUNK, 4), 256, 0, stream>>>(kbuf, vbuf, rbuf, time_decay, time_first,
                                                  sA, sB, sP, arwkv, aa_out, bb_out, pp_out);
    // d6: output GEMM + residual
    gemm_o<<<1024, 256, 0, stream>>>(arwkv, Wt + 3 * C2, out, x);
}